// Round 15
// baseline (185.605 us; speedup 1.0000x reference)
//
#include <hip/hip_runtime.h>

#define TT    2000
#define NG    4000
#define WARM  365
#define LENF  15
#define NPHY  12
#define BLK   60                  // timesteps per staged block
#define PAIRS (BLK / 2)           // f32x2 pairs per ring slot
#define SLOTW 64                  // dwords per step in stage LDS (48 used + pad)
#define SLOTD (BLK * SLOTW)       // 3840 dwords per stage slot
#define NBLK  34                  // 34*60 = 2040 steps (covers TT, stores gated)
#define ROWF  (3 * NG)            // 12000 floats per timestep row

typedef const float __attribute__((address_space(1)))* gptr_t;
typedef float __attribute__((address_space(3)))* lptr_t;
typedef __attribute__((ext_vector_type(2))) float f32x2;

// Quad-wide sum via DPP (VALU-only; no LDS pipe).
__device__ __forceinline__ float quad_sum(float x) {
    int a = __builtin_amdgcn_update_dpp(0, __float_as_int(x), 0xB1, 0xF, 0xF, true);
    float s = x + __int_as_float(a);
    int b = __builtin_amdgcn_update_dpp(0, __float_as_int(s), 0x4E, 0xF, 0xF, true);
    return s + __int_as_float(b);
}

#define WG_BARRIER() asm volatile("s_waitcnt lgkmcnt(0)\n\ts_barrier" ::: "memory")

// Wave-specialized pipeline, 4 waves / WG, 16 cells, 250 WGs.
// r15: CODE-SIZE attack. r14's fully-unrolled body was ~4060 inst (~32KB)
// = L1i capacity; 4 waves stream 4 different 8KB regions per iter -> fetch
// thrash -> issue serializes (measured iter == sum-of-instructions). All
// stage bodies are now short chunked loops (#pragma unroll 1) with software
// prefetch of the next chunk's LDS data; total hot code ~3-4KB.
__global__ __launch_bounds__(256, 1) void hbv_pipe_kernel(
    const float* __restrict__ xphy,   // [T, G, 3]
    const float* __restrict__ prm,    // [1, G, 50]
    float* __restrict__ out)          // [T-WARM, G]
{
    // rings first, stage LAST (prefetch overreads land inside the allocation)
    __shared__ f32x2 s_rt [2 * PAIRS * 64];     // snow -> soil     (30720 B)
    __shared__ f32x2 s_rex[2 * PAIRS * 64];     // soil -> response (30720 B)
    __shared__ f32x2 s_q  [2 * PAIRS * 64];     // response -> conv (30720 B)
    __shared__ float s_stage[3 * SLOTD];        // 46080 B input stage ring

    const int lane = threadIdx.x & 63;
    const int wid  = threadIdx.x >> 6;    // 0..3
    const int g0   = blockIdx.x * 16;     // 250 workgroups * 16 cells
    const int cell = lane >> 2;
    const int g    = g0 + cell;
    const int m    = lane & 3;

    const float* pg = prm + (size_t)g * (NPHY * 4 + 2);

    const float lb[NPHY] = {1.0f, 50.0f, 0.05f, 0.01f, 0.001f, 0.2f, 0.0f, 0.0f, -2.5f, 0.5f, 0.0f, 0.0f};
    const float ub[NPHY] = {6.0f, 1000.0f, 0.9f, 0.5f, 0.2f, 1.0f, 10.0f, 100.0f, 2.5f, 10.0f, 0.1f, 0.2f};
    float ph[NPHY];
    #pragma unroll
    for (int i = 0; i < NPHY; ++i)
        ph[i] = lb[i] + pg[i * 4 + m] * (ub[i] - lb[i]);

    const float beta = ph[0], fc = ph[1], k0 = ph[2], k1 = ph[3], k2 = ph[4],
                lp = ph[5], perc = ph[6], uzl = ph[7], ttp = ph[8],
                cfmax = ph[9], cfr = ph[10], cwh = ph[11];
    const float rlpfc  = 1.0f / (lp * fc);
    const float cfrcf  = cfr * cfmax;
    const float blfc   = beta * __builtin_amdgcn_logf(1.0f / fc);  // beta*log2(1/fc)
    const float onemk1 = 1.0f - k1;
    const float onemk2 = 1.0f - k2;

    // Routing weights (gammaln / th^aa cancel under normalization); 0.25 folded.
    const float aa  = fmaxf(pg[48] * 2.9f, 0.0f) + 0.1f;
    const float th  = fmaxf(pg[49] * 6.5f, 0.0f) + 0.5f;
    const float rth = 1.0f / th;
    const float LOG2E = 1.4426950408889634f;
    float w[LENF];
    float wsum = 0.0f;
    #pragma unroll
    for (int k = 0; k < LENF; ++k) {
        const float tg = (float)k + 0.5f;
        const float e = (aa - 1.0f) * __builtin_log2f(tg) - tg * rth * LOG2E;
        w[k] = __builtin_amdgcn_exp2f(e);
        wsum += w[k];
    }
    const float rw = 0.25f / wsum;
    #pragma unroll
    for (int k = 0; k < LENF; ++k) w[k] *= rw;

    // Per-wave persistent states
    float snowpack = 0.001f, meltwater = 0.001f;   // wave0
    float sm = 0.001f;                             // wave1
    float suz = 0.001f, slz = 0.001f;              // wave2
    float qw[20];                                  // wave3 sliding q window
    #pragma unroll
    for (int d = 0; d < 20; ++d) qw[d] = 0.0f;

    const int loffd = (lane < 48 ? lane : 47);

    // ---- chunked staging: each wave loads 15 steps of a block ----
    auto stage_blk = [&](int bb) {
        const int tb = bb * BLK + wid * 15;
        float* ldst = &s_stage[(bb % 3) * SLOTD + (wid * 15) * SLOTW];
        #pragma unroll 1
        for (int c = 0; c < 15; ++c) {
            int t = tb + c; t = (t < TT) ? t : (TT - 1);
            const float* gsrc = xphy + (size_t)t * ROWF + g0 * 3 + loffd;
            __builtin_amdgcn_global_load_lds((gptr_t)gsrc, (lptr_t)ldst, 4, 0, 0);
            ldst += SLOTW;
        }
    };

#define SNOWSTEP(P_, T_, RT_) do {                                   \
    const float dT_   = (T_) - ttp;                                  \
    const float rain_ = ((T_) >= ttp) ? (P_) : 0.0f;                 \
    const float snw_  = (P_) - rain_;                                \
    const float mc_   = cfmax * fmaxf(dT_, 0.0f);                    \
    const float rc_   = cfrcf * fmaxf(-dT_, 0.0f);                   \
    snowpack += snw_;                                                \
    const float melt_ = fminf(mc_, snowpack);                        \
    meltwater += melt_;                                              \
    snowpack  -= melt_;                                              \
    const float rf_ = fminf(rc_, meltwater);                         \
    meltwater -= rf_;                                                \
    snowpack  += rf_;                                                \
    const float ts_ = fmaxf(fmaf(-cwh, snowpack, meltwater), 0.0f);  \
    meltwater -= ts_;                                                \
    (RT_) = rain_ + ts_;                                             \
} while (0)

#define SOILSTEP(RT_, EV_, REX_) do {                                         \
    const float sw_  = __builtin_amdgcn_exp2f(fmaf(beta, __builtin_amdgcn_logf(sm), blfc)); \
    const float sp_  = sm + (RT_);                                            \
    const float sm1_ = fmaf(-(RT_), sw_, sp_);                                \
    const float sm2_ = fminf(sm1_, fc);                                       \
    const float uf_  = fmaxf(fmaf(-(EV_), rlpfc, 1.0f), 0.0f);                \
    sm = fmaxf(fmaxf(sm2_ * uf_, sm2_ - (EV_)), 1e-5f);                       \
    (REX_) = fmaf((RT_), sw_, sm1_ - sm2_);                                   \
} while (0)

#define RESPSTEP(REX_, Q_) do {                                      \
    const float s1_ = suz + (REX_);                                  \
    const float pc_ = fminf(s1_, perc);                              \
    const float sA_ = s1_ - pc_;                                     \
    const float tq_ = fmaxf(sA_ - uzl, 0.0f);                        \
    const float q0_ = k0 * tq_;                                      \
    const float sB_ = fmaf(-k0, tq_, sA_);                           \
    const float q1_ = k1 * sB_;                                      \
    suz = sB_ * onemk1;                                              \
    const float sl_ = slz + pc_;                                     \
    const float q2_ = k2 * sl_;                                      \
    slz = sl_ * onemk2;                                              \
    (Q_) = quad_sum(q0_ + q1_ + q2_);                                \
} while (0)

    stage_blk(0);
    asm volatile("s_waitcnt vmcnt(0)" ::: "memory");
    WG_BARRIER();

    for (int i = 0; i <= NBLK + 2; ++i) {
        if (i < NBLK - 1) stage_blk(i + 1);

        if (wid == 0) {
            // ---- snow chain, block i (4-step chunks, prefetched) ----
            if (i < NBLK) {
                const float* sb = &s_stage[(i % 3) * SLOTD + cell * 3];
                f32x2* rtw = &s_rt[(i & 1) * (PAIRS * 64) + lane];
                float P0 = sb[0], T0 = sb[1], P1 = sb[SLOTW], T1 = sb[SLOTW + 1],
                      P2 = sb[2 * SLOTW], T2 = sb[2 * SLOTW + 1],
                      P3 = sb[3 * SLOTW], T3 = sb[3 * SLOTW + 1];
                sb += 4 * SLOTW;
                #pragma unroll 1
                for (int ch = 0; ch < BLK / 4; ++ch) {
                    const float nP0 = sb[0], nT0 = sb[1], nP1 = sb[SLOTW], nT1 = sb[SLOTW + 1],
                                nP2 = sb[2 * SLOTW], nT2 = sb[2 * SLOTW + 1],
                                nP3 = sb[3 * SLOTW], nT3 = sb[3 * SLOTW + 1];
                    sb += 4 * SLOTW;
                    float r0, r1, r2, r3;
                    SNOWSTEP(P0, T0, r0); SNOWSTEP(P1, T1, r1);
                    SNOWSTEP(P2, T2, r2); SNOWSTEP(P3, T3, r3);
                    f32x2 a; a[0] = r0; a[1] = r1; rtw[0] = a;
                    f32x2 b; b[0] = r2; b[1] = r3; rtw[64] = b;
                    rtw += 128;
                    P0 = nP0; T0 = nT0; P1 = nP1; T1 = nT1;
                    P2 = nP2; T2 = nT2; P3 = nP3; T3 = nT3;
                }
            }
        } else if (wid == 1) {
            // ---- soil chain, block i-1 (4-step chunks, prefetched) ----
            const int b = i - 1;
            if (b >= 0 && b < NBLK) {
                const float* sbe = &s_stage[(b % 3) * SLOTD + cell * 3 + 2];
                const f32x2* rtr = &s_rt[(b & 1) * (PAIRS * 64) + lane];
                f32x2* rexw = &s_rex[(b & 1) * (PAIRS * 64) + lane];
                f32x2 rA = rtr[0], rB = rtr[64];
                float e0 = sbe[0], e1 = sbe[SLOTW], e2 = sbe[2 * SLOTW], e3 = sbe[3 * SLOTW];
                rtr += 128; sbe += 4 * SLOTW;
                #pragma unroll 1
                for (int ch = 0; ch < BLK / 4; ++ch) {
                    const f32x2 nA = rtr[0], nB = rtr[64];
                    const float ne0 = sbe[0], ne1 = sbe[SLOTW],
                                ne2 = sbe[2 * SLOTW], ne3 = sbe[3 * SLOTW];
                    rtr += 128; sbe += 4 * SLOTW;
                    float x0, x1, x2, x3;
                    SOILSTEP(rA[0], e0, x0); SOILSTEP(rA[1], e1, x1);
                    SOILSTEP(rB[0], e2, x2); SOILSTEP(rB[1], e3, x3);
                    f32x2 a; a[0] = x0; a[1] = x1; rexw[0] = a;
                    f32x2 b2; b2[0] = x2; b2[1] = x3; rexw[64] = b2;
                    rexw += 128;
                    rA = nA; rB = nB; e0 = ne0; e1 = ne1; e2 = ne2; e3 = ne3;
                }
            }
        } else if (wid == 2) {
            // ---- response chain + quad mean, block i-2 (4-step chunks) ----
            const int b = i - 2;
            if (b >= 0 && b < NBLK) {
                const f32x2* rexr = &s_rex[(b & 1) * (PAIRS * 64) + lane];
                f32x2* qwr = &s_q[(b & 1) * (PAIRS * 64) + lane];
                f32x2 rA = rexr[0], rB = rexr[64];
                rexr += 128;
                #pragma unroll 1
                for (int ch = 0; ch < BLK / 4; ++ch) {
                    const f32x2 nA = rexr[0], nB = rexr[64];
                    rexr += 128;
                    float q0, q1, q2, q3;
                    RESPSTEP(rA[0], q0); RESPSTEP(rA[1], q1);
                    RESPSTEP(rB[0], q2); RESPSTEP(rB[1], q3);
                    f32x2 a; a[0] = q0; a[1] = q1; qwr[0] = a;
                    f32x2 b2; b2[0] = q2; b2[1] = q3; qwr[64] = b2;
                    qwr += 128;
                    rA = nA; rB = nB;
                }
            }
        } else {
            // ---- 15-tap conv + stores, block i-3 (6-step chunks, window) ----
            const int b = i - 3;
            if (b >= 0 && b < NBLK) {
                const int t0 = b * BLK;
                const f32x2* qr = &s_q[(b & 1) * (PAIRS * 64) + lane];
                f32x2 c0 = qr[0], c1 = qr[64], c2 = qr[128];
                qr += 192;
                #pragma unroll 1
                for (int ch = 0; ch < BLK / 6; ++ch) {
                    const f32x2 n0 = qr[0], n1 = qr[64], n2 = qr[128];
                    qr += 192;
                    #pragma unroll
                    for (int d = 0; d < 14; ++d) qw[d] = qw[d + 6];
                    qw[14] = c0[0]; qw[15] = c0[1]; qw[16] = c1[0];
                    qw[17] = c1[1]; qw[18] = c2[0]; qw[19] = c2[1];
                    const int jb = ch * 6;
                    #pragma unroll
                    for (int c = 0; c < 6; ++c) {
                        float o = w[0] * qw[14 + c];
                        #pragma unroll
                        for (int k = 1; k < LENF; ++k)
                            o = fmaf(w[k], qw[14 + c - k], o);
                        const int j = jb + c;
                        const int t = t0 + j;
                        if (((j & 3) == m) && t >= WARM && t < TT)
                            out[(size_t)(t - WARM) * NG + g] = o;
                    }
                    c0 = n0; c1 = n1; c2 = n2;
                }
            }
        }

        asm volatile("s_waitcnt vmcnt(0)" ::: "memory");
        WG_BARRIER();
    }
}

extern "C" void kernel_launch(void* const* d_in, const int* in_sizes, int n_in,
                              void* d_out, int out_size, void* d_ws, size_t ws_size,
                              hipStream_t stream) {
    const float* xphy = (const float*)d_in[0];   // [2000, 4000, 3]
    const float* prm  = (const float*)d_in[1];   // [1, 4000, 50]
    float* out = (float*)d_out;                  // [1635, 4000, 1]

    hbv_pipe_kernel<<<NG / 16, 256, 0, stream>>>(xphy, prm, out);
}

// Round 17
// 142.950 us; speedup vs baseline: 1.2984x; 1.2984x over previous
//
#include <hip/hip_runtime.h>

#define TT    2000
#define NG    4000
#define WARM  365
#define LENF  15
#define NPHY  12
#define BLK   60                  // timesteps per staged block
#define NBLK  34                  // 34*60 = 2040 steps (covers TT, stores gated)
#define SLOTW 64                  // dwords per step in stage slot (48 used + pad)
#define SLOT  (BLK * SLOTW)       // 3840 floats per stage slot
#define ROWF  (3 * NG)            // floats per timestep row

typedef const float __attribute__((address_space(1)))* gptr_t;
typedef float __attribute__((address_space(3)))* lptr_t;
typedef __attribute__((ext_vector_type(2))) float f32x2;

// Quad-wide sum via DPP (VALU-only). After both swaps all 4 lanes hold the sum.
__device__ __forceinline__ float quad_sum(float x) {
    int a = __builtin_amdgcn_update_dpp(0, __float_as_int(x), 0xB1, 0xF, 0xF, true);
    float s = x + __int_as_float(a);
    int b = __builtin_amdgcn_update_dpp(0, __float_as_int(s), 0x4E, 0xF, 0xF, true);
    return s + __int_as_float(b);
}

#define WG_BARRIER() asm volatile("s_waitcnt lgkmcnt(0)\n\ts_barrier" ::: "memory")

// Kernel 1: serial region only. 3 waves / WG (192 thr), 16 cells, 250 WGs.
//   wave0: snow chain (block i)   -> s_rt ring
//   wave1: soil chain (block i-1) -> s_rex ring
//   wave2: response chain + quad mean (block i-2) -> qm workspace (global)
// Staging: r14's PROVEN discipline — size-4 global_load_lds, SLOTW=64 padded
// steps, distributed 20 steps/wave, vmcnt(0)+barrier each iteration (r16's
// size-12 packed staging produced NaN: only sizes 4/16 are HW-verified).
// Conv is evicted to kernel 2: regime is per-WG instruction issue (r13/r14),
// so the ~18 inst/step of conv+ring come straight off the critical path.
__global__ __launch_bounds__(192, 1) void hbv_chain_kernel(
    const float* __restrict__ xphy,   // [T, G, 3]
    const float* __restrict__ prm,    // [1, G, 50]
    float* __restrict__ qm)           // [T, G] workspace: quad-SUM of q
{
    __shared__ float s_stage[3 * SLOT];          // 46080 B, 3-slot ring
    __shared__ f32x2 s_rt [2 * (BLK / 2) * 64];  // 30720 B
    __shared__ f32x2 s_rex[2 * (BLK / 2) * 64];  // 30720 B

    const int lane = threadIdx.x & 63;
    const int wid  = threadIdx.x >> 6;    // 0..2
    const int g0   = blockIdx.x * 16;
    const int cell = lane >> 2;
    const int g    = g0 + cell;
    const int m    = lane & 3;

    const float* pg = prm + (size_t)g * (NPHY * 4 + 2);

    const float lb[NPHY] = {1.0f, 50.0f, 0.05f, 0.01f, 0.001f, 0.2f, 0.0f, 0.0f, -2.5f, 0.5f, 0.0f, 0.0f};
    const float ub[NPHY] = {6.0f, 1000.0f, 0.9f, 0.5f, 0.2f, 1.0f, 10.0f, 100.0f, 2.5f, 10.0f, 0.1f, 0.2f};
    float ph[NPHY];
    #pragma unroll
    for (int i = 0; i < NPHY; ++i)
        ph[i] = lb[i] + pg[i * 4 + m] * (ub[i] - lb[i]);

    const float beta = ph[0], fc = ph[1], k0 = ph[2], k1 = ph[3], k2 = ph[4],
                lp = ph[5], perc = ph[6], uzl = ph[7], ttp = ph[8],
                cfmax = ph[9], cfr = ph[10], cwh = ph[11];
    const float rlpfc  = 1.0f / (lp * fc);
    const float cfrcf  = cfr * cfmax;
    const float blfc   = beta * __builtin_amdgcn_logf(1.0f / fc);
    const float onemk1 = 1.0f - k1;
    const float onemk2 = 1.0f - k2;

    // Per-wave persistent states
    float snowpack = 0.001f, meltwater = 0.001f;   // wave0
    float sm = 0.001f;                             // wave1
    float suz = 0.001f, slz = 0.001f;              // wave2

    const int loffd = (lane < 48 ? lane : 47);

    // distributed staging: each of the 3 waves loads 20 steps of block b
    auto stage_blk = [&](int b) {
        const int tb = b * BLK + wid * 20;
        float* ldst = &s_stage[(b % 3) * SLOT + (wid * 20) * SLOTW];
        #pragma unroll
        for (int c = 0; c < 20; ++c) {
            int t = tb + c; t = (t < TT) ? t : (TT - 1);
            const float* src = xphy + (size_t)t * ROWF + g0 * 3 + loffd;
            __builtin_amdgcn_global_load_lds((gptr_t)src, (lptr_t)(ldst + c * SLOTW), 4, 0, 0);
        }
    };

    stage_blk(0);
    asm volatile("s_waitcnt vmcnt(0)" ::: "memory");
    WG_BARRIER();

    for (int i = 0; i <= NBLK + 1; ++i) {
        if (i < NBLK - 1) stage_blk(i + 1);   // lands by end-of-iter drain

        if (wid == 0) {
            // ---- snow chain, block i ----
            if (i < NBLK) {
                const float* sb = &s_stage[(i % 3) * SLOT + cell * 3];
                f32x2* rtw = &s_rt[(i & 1) * ((BLK / 2) * 64) + lane];
                float rt_even = 0.0f;
                #pragma unroll
                for (int j = 0; j < BLK; ++j) {
                    const float Pt = sb[j * SLOTW];
                    const float Tm = sb[j * SLOTW + 1];
                    const float dT      = Tm - ttp;
                    const float rain    = (Tm >= ttp) ? Pt : 0.0f;
                    const float snw     = Pt - rain;
                    const float meltcap = cfmax * fmaxf(dT, 0.0f);
                    const float refcap  = cfrcf * fmaxf(-dT, 0.0f);
                    snowpack += snw;
                    const float melt = fminf(meltcap, snowpack);
                    meltwater += melt;
                    snowpack  -= melt;
                    const float refreeze = fminf(refcap, meltwater);
                    meltwater -= refreeze;
                    snowpack  += refreeze;
                    const float tosoil = fmaxf(fmaf(-cwh, snowpack, meltwater), 0.0f);
                    meltwater -= tosoil;
                    const float rt = rain + tosoil;
                    if ((j & 1) == 0) rt_even = rt;
                    else { f32x2 pr; pr[0] = rt_even; pr[1] = rt; rtw[(j >> 1) * 64] = pr; }
                }
            }
        } else if (wid == 1) {
            // ---- soil-moisture chain, block i-1 ----
            const int b = i - 1;
            if (b >= 0 && b < NBLK) {
                const float* sbe = &s_stage[(b % 3) * SLOT + cell * 3 + 2];  // ev
                const f32x2* rtr = &s_rt[(b & 1) * ((BLK / 2) * 64) + lane];
                f32x2* rexw = &s_rex[(b & 1) * ((BLK / 2) * 64) + lane];
                f32x2 rp; rp[0] = 0.0f; rp[1] = 0.0f;
                float rex_even = 0.0f;
                #pragma unroll
                for (int j = 0; j < BLK; ++j) {
                    if ((j & 1) == 0) rp = rtr[(j >> 1) * 64];
                    const float rt = ((j & 1) == 0) ? rp[0] : rp[1];
                    const float ev = sbe[j * SLOTW];
                    const float sw    = __builtin_amdgcn_exp2f(fmaf(beta, __builtin_amdgcn_logf(sm), blfc));
                    const float sp    = sm + rt;
                    const float sm1   = fmaf(-rt, sw, sp);
                    const float sm2   = fminf(sm1, fc);
                    const float uf    = fmaxf(fmaf(-ev, rlpfc, 1.0f), 0.0f);
                    sm = fmaxf(fmaxf(sm2 * uf, sm2 - ev), 1e-5f);
                    const float rex = fmaf(rt, sw, sm1 - sm2);
                    if ((j & 1) == 0) rex_even = rex;
                    else { f32x2 pr; pr[0] = rex_even; pr[1] = rex; rexw[(j >> 1) * 64] = pr; }
                }
            }
        } else {
            // ---- response chain + quad mean -> qm store, block i-2 ----
            const int b = i - 2;
            if (b >= 0 && b < NBLK) {
                const int t0 = b * BLK;
                const f32x2* rexr = &s_rex[(b & 1) * ((BLK / 2) * 64) + lane];
                f32x2 rp; rp[0] = 0.0f; rp[1] = 0.0f;
                float ov[BLK / 4];
                #pragma unroll
                for (int k = 0; k < BLK / 4; ++k) ov[k] = 0.0f;
                #pragma unroll
                for (int j = 0; j < BLK; ++j) {
                    if ((j & 1) == 0) rp = rexr[(j >> 1) * 64];
                    const float rex = ((j & 1) == 0) ? rp[0] : rp[1];
                    const float suz1 = suz + rex;
                    const float prc  = fminf(suz1, perc);
                    const float suzA = suz1 - prc;
                    const float tq   = fmaxf(suzA - uzl, 0.0f);
                    const float q0   = k0 * tq;
                    const float suzB = fmaf(-k0, tq, suzA);
                    const float q1   = k1 * suzB;
                    suz = suzB * onemk1;
                    const float sl1  = slz + prc;
                    const float q2   = k2 * sl1;
                    slz = sl1 * onemk2;
                    const float q = quad_sum(q0 + q1 + q2);   // quad SUM
                    const bool sel = ((j & 3) == m);
                    ov[j >> 2] = sel ? q : ov[j >> 2];        // j>>2 compile-time
                }
                #pragma unroll
                for (int k = 0; k < BLK / 4; ++k) {
                    const int t = t0 + k * 4 + m;
                    if (t < TT) qm[(size_t)t * NG + g] = ov[k];
                }
            }
        }

        // drain own staging loads (r14 discipline), then sync all waves
        asm volatile("s_waitcnt vmcnt(0)" ::: "memory");
        WG_BARRIER();
    }
}

// Kernel 2: 15-tap routing conv — embarrassingly parallel over (t, g),
// memory-bound. Recomputes w from compile-time log2(k+0.5) constants;
// gammaln/th^aa cancel under normalization; 0.25 multiplier-mean folded.
__global__ __launch_bounds__(256) void hbv_conv_kernel(
    const float* __restrict__ qm,     // [T, G] quad-sums
    const float* __restrict__ prm,    // [1, G, 50]
    float* __restrict__ out)          // [T-WARM, G]
{
    const int g = blockIdx.x * 256 + threadIdx.x;
    if (g >= NG) return;
    const int t0 = WARM + blockIdx.y * 8;

    const float* pr = prm + (size_t)g * 50;
    const float aa  = fmaxf(pr[48] * 2.9f, 0.0f) + 0.1f;
    const float th  = fmaxf(pr[49] * 6.5f, 0.0f) + 0.5f;
    const float aam1 = aa - 1.0f;
    const float rthl = 1.4426950408889634f / th;

    const float L2TG[LENF] = {
        -1.0f, 0.5849625007211562f, 1.3219280948873623f, 1.8073549220576042f,
        2.169925001442312f, 2.4594316186372973f, 2.700439718141092f,
        2.9068905956085187f, 3.087462841250339f, 3.247927513443585f,
        3.3923174227787602f, 3.523561956057013f, 3.643856189774724f,
        3.754887502163468f, 3.857980995127572f };

    float w[LENF];
    float wsum = 0.0f;
    #pragma unroll
    for (int k = 0; k < LENF; ++k) {
        const float tg = (float)k + 0.5f;
        w[k] = __builtin_amdgcn_exp2f(fmaf(aam1, L2TG[k], -tg * rthl));
        wsum += w[k];
    }
    const float rw = 0.25f / wsum;   // 0.25 = mean over the 4 multipliers

    float qv[22];
    #pragma unroll
    for (int j = 0; j < 22; ++j) {
        int t = t0 - 14 + j; t = (t < TT) ? t : (TT - 1);
        qv[j] = qm[(size_t)t * NG + g];
    }
    #pragma unroll
    for (int c = 0; c < 8; ++c) {
        float o = 0.0f;
        #pragma unroll
        for (int k = 0; k < LENF; ++k)
            o = fmaf(w[k], qv[14 + c - k], o);
        const int t = t0 + c;
        if (t < TT) out[(size_t)(t - WARM) * NG + g] = o * rw;
    }
}

extern "C" void kernel_launch(void* const* d_in, const int* in_sizes, int n_in,
                              void* d_out, int out_size, void* d_ws, size_t ws_size,
                              hipStream_t stream) {
    const float* xphy = (const float*)d_in[0];   // [2000, 4000, 3]
    const float* prm  = (const float*)d_in[1];   // [1, 4000, 50]
    float* out = (float*)d_out;                  // [1635, 4000, 1]
    float* qm  = (float*)d_ws;                   // [2000, 4000] = 32 MB

    hbv_chain_kernel<<<NG / 16, 192, 0, stream>>>(xphy, prm, qm);

    dim3 grid2((NG + 255) / 256, (TT - WARM + 7) / 8);   // 16 x 205
    hbv_conv_kernel<<<grid2, 256, 0, stream>>>(qm, prm, out);
}